// Round 15
// baseline (195.652 us; speedup 1.0000x reference)
//
#include <hip/hip_runtime.h>

#define HW 16384   // 128*128

typedef __bf16 bf16x8 __attribute__((ext_vector_type(8)));
typedef __bf16 bf16x4 __attribute__((ext_vector_type(4)));
typedef float  f32x4  __attribute__((ext_vector_type(4)));
typedef float  f32x2  __attribute__((ext_vector_type(2)));

// ---------- prep 0: w_t[128][448] bf16 (k = t*48+m, zero-pad), wc_bf[48][64] ----------
__global__ __launch_bounds__(256)
void prep_w(const float* __restrict__ we, const float* __restrict__ wc,
            __bf16* __restrict__ wt, __bf16* __restrict__ wcb) {
    int idx = blockIdx.x * 256 + threadIdx.x;
    if (idx < 128 * 448) {
        int e = idx / 448, k = idx % 448;
        float v = 0.f;
        if (e < 100 && k < 432) {
            int t = k / 48, m = k % 48;
            v = we[(e * 48 + m) * 9 + t];
        }
        wt[idx] = (__bf16)v;
    } else {
        idx -= 128 * 448;
        if (idx < 48 * 64) wcb[idx] = (__bf16)wc[idx];
    }
}

// ---------- prep 1: x -> xt [b][pos][64] bf16  AND  y1 [b][pos][48] bf16 ----------
// y1 = relu(conv1x1(x)+bc) via MFMA on the in-LDS f32 tile (swapped operands).
__global__ __launch_bounds__(256, 2)
void prep_xty1(const float* __restrict__ x, const __bf16* __restrict__ wcb,
               const float* __restrict__ bc,
               __bf16* __restrict__ xt, __bf16* __restrict__ y1o) {
    __shared__ __align__(16) float lds[256 * 65];      // 66,560 B
    __bf16* y1s = (__bf16*)lds;                        // [256][56] union (after barrier)

    const int b = blockIdx.x & 7, chunk = blockIdx.x >> 3;   // XCD-pin batch
    const int t = threadIdx.x;
    const int lane = t & 63, wv = t >> 6;
    const int lgp = lane >> 4, lr = lane & 15;
    const int pos0 = chunk * 256;

    // ---- phase 1: coalesced f32 load + LDS transpose
    const float* xb = x + (size_t)b * 64 * HW + pos0;
    for (int c = 0; c < 64; ++c)
        lds[t * 65 + c] = xb[(size_t)c * HW + t];
    __syncthreads();

    // ---- phase 2: xt stores (wave-contiguous) + y1 A-fragments into regs
    {
        const int q = t & 3, pp = t >> 2;
        #pragma unroll
        for (int it = 0; it < 4; ++it) {
            int pos = it * 64 + pp;
            __bf16* o = xt + ((size_t)b * HW + pos0 + pos) * 64 + q * 16;
            bf16x8 v0, v1;
            #pragma unroll
            for (int e = 0; e < 8; ++e) {
                v0[e] = (__bf16)lds[pos * 65 + q * 16 + e];
                v1[e] = (__bf16)lds[pos * 65 + q * 16 + 8 + e];
            }
            *(bf16x8*)o       = v0;
            *(bf16x8*)(o + 8) = v1;
        }
    }
    bf16x8 af[4][2];                       // 4 M-tiles x 2 K-chunks, lane pixel = lr
    #pragma unroll
    for (int i = 0; i < 4; ++i) {
        int pix = (wv * 4 + i) * 16 + lr;
        #pragma unroll
        for (int kc = 0; kc < 2; ++kc)
            #pragma unroll
            for (int e = 0; e < 8; ++e)
                af[i][kc][e] = (__bf16)lds[pix * 65 + kc * 32 + lgp * 8 + e];
    }
    __syncthreads();

    // ---- phase 3: MFMA conv1x1 (swapped: D col = own pixel) -> y1s spill
    {
        bf16x8 bw[3][2];
        f32x4 bias4[3];
        #pragma unroll
        for (int nt = 0; nt < 3; ++nt) {
            bias4[nt] = *(const f32x4*)(bc + nt * 16 + lgp * 4);
            #pragma unroll
            for (int kc = 0; kc < 2; ++kc)
                bw[nt][kc] = *(const bf16x8*)(wcb + (nt * 16 + lr) * 64 + kc * 32 + lgp * 8);
        }
        #pragma unroll
        for (int i = 0; i < 4; ++i) {
            int pix = (wv * 4 + i) * 16 + lr;
            #pragma unroll
            for (int nt = 0; nt < 3; ++nt) {
                f32x4 cc = bias4[nt];
                cc = __builtin_amdgcn_mfma_f32_16x16x32_bf16(bw[nt][0], af[i][0], cc, 0, 0, 0);
                cc = __builtin_amdgcn_mfma_f32_16x16x32_bf16(bw[nt][1], af[i][1], cc, 0, 0, 0);
                bf16x4 o4;
                #pragma unroll
                for (int r = 0; r < 4; ++r) o4[r] = (__bf16)fmaxf(cc[r], 0.f);
                *(bf16x4*)(y1s + pix * 56 + nt * 16 + lgp * 4) = o4;
            }
        }
    }
    __syncthreads();

    // ---- phase 4: y1s -> global [256][48], wave-contiguous 16B stores
    __bf16* yo = y1o + (size_t)(b * HW + pos0) * 48;
    #pragma unroll
    for (int i = 0; i < 6; ++i) {
        int c = i * 256 + t;                     // 1536 chunks of 8 halfwords
        int pix = (c * 10923) >> 16;             // c / 6
        int mc  = c - pix * 6;
        bf16x8 v = *(bf16x8*)(y1s + pix * 56 + mc * 8);
        *(bf16x8*)(yo + (size_t)c * 8) = v;
    }
}

// ---------- kernel W: y1-halo stage -> conv3x3(MFMA) -> packed f16x2 logits ----------
// 256 thr, tile 16x16, 512 blocks (2/CU). LDS: y1[344][56] -> lgt[256][116]
__global__ __launch_bounds__(256, 2)
void carafe_weights(const __bf16* __restrict__ y1g,
                    const __bf16* __restrict__ wt, const float* __restrict__ be,
                    unsigned int* __restrict__ wnp) {   // [(b*2+s2)*25+k][tile*256+pix]
    __shared__ __align__(16) char smem[59392];
    __bf16*    y1  = (__bf16*)smem;    // [344][56]
    _Float16*  lgt = (_Float16*)smem;  // [256][116]

    const int tid = threadIdx.x;
    const int lane = tid & 63, wv = tid >> 6;
    const int lgp = lane >> 4, lr = lane & 15;
    const int b = blockIdx.x & 7, tile = blockIdx.x >> 3;    // XCD-pin batch
    const int h0 = (tile >> 3) << 4, w0 = (tile & 7) << 4;

    // ===== stage y1 halo (18x18 pos x 48 ch), zero outside image
    const __bf16* y1b = y1g + (size_t)b * HW * 48;
    #pragma unroll
    for (int it = 0; it < 8; ++it) {
        int id = it * 256 + tid;                 // (hr, wc, mc): 18*18*6 = 1944
        if (id < 1944) {
            int hr  = (id * 607) >> 16;          // id / 108
            int rem = id - hr * 108;
            int wc  = (rem * 10923) >> 16;       // rem / 6
            int mc  = rem - wc * 6;
            int hy = h0 - 1 + hr, wx = w0 - 1 + wc;
            bf16x8 v = {};
            if (hy >= 0 && hy < 128 && wx >= 0 && wx < 128)
                v = *(const bf16x8*)(y1b + (size_t)(hy * 128 + wx) * 48 + mc * 8);
            *(bf16x8*)(y1 + (hr * 18 + wc) * 56 + mc * 8) = v;
        }
    }
    for (int i = tid; i < 1120; i += 256)
        y1[324 * 56 + i] = (__bf16)0.f;          // rows 324..343 (K-pad t=9 reads)
    __syncthreads();

    // ===== P2: logits[256px][112] = Ycol[px][432] * W[432][112], 4 waves x 4 px-tiles
    f32x4 acc[4][7];
    #pragma unroll
    for (int ot = 0; ot < 7; ++ot) {
        int o_ = ot * 16 + lr;
        float bz = (o_ < 100) ? be[o_] : 0.f;
        #pragma unroll
        for (int i = 0; i < 4; ++i) acc[i][ot] = {bz, bz, bz, bz};
    }
    const int ptg0 = wv * 4;

    auto ldA = [&](bf16x8 A[4], int kc) {
        int Kb = kc * 32 + lgp * 8;
        int t  = (Kb * 683) >> 15;  int m0 = Kb - t * 48;   // k = t*48+m
        int ty = (t * 11) >> 5;     int tx = t - ty * 3;
        int base = ty * 18 + lr + tx;
        #pragma unroll
        for (int i = 0; i < 4; ++i)
            A[i] = *(const bf16x8*)(y1 + ((ptg0 + i) * 18 + base) * 56 + m0);
    };
    auto ldB = [&](bf16x8 B[7], int kc) {
        #pragma unroll
        for (int j = 0; j < 7; ++j)
            B[j] = *(const bf16x8*)(wt + (j * 16 + lr) * 448 + kc * 32 + lgp * 8);
    };
    auto mm = [&](bf16x8 A[4], bf16x8 B[7]) {
        #pragma unroll
        for (int i = 0; i < 4; ++i)
            #pragma unroll
            for (int j = 0; j < 7; ++j)
                acc[i][j] = __builtin_amdgcn_mfma_f32_16x16x32_bf16(A[i], B[j], acc[i][j], 0, 0, 0);
    };

    bf16x8 A0[4], B0[7], A1[4], B1[7];
    ldA(A0, 0); ldB(B0, 0);
    #pragma unroll
    for (int kc = 0; kc < 14; kc += 2) {
        if (kc + 1 < 14) { ldA(A1, kc + 1); ldB(B1, kc + 1); }
        mm(A0, B0);
        if (kc + 2 < 14) { ldA(A0, kc + 2); ldB(B0, kc + 2); }
        if (kc + 1 < 14) mm(A1, B1);
    }
    __syncthreads();   // y1 dead

    // ===== P3: spill logits to LDS [256][116] fp16
    #pragma unroll
    for (int i = 0; i < 4; ++i)
        #pragma unroll
        for (int j = 0; j < 7; ++j) {
            int o_ = j * 16 + lr;
            #pragma unroll
            for (int r = 0; r < 4; ++r) {
                int p = (ptg0 + i) * 16 + lgp * 4 + r;
                lgt[p * 116 + o_] = (_Float16)acc[i][j][r];
            }
        }
    __syncthreads();

    // ===== P4: pack f16x2 logit pairs, tile-local contiguous store
    const _Float16* lrow = lgt + tid * 116;
    #pragma unroll
    for (int s2 = 0; s2 < 2; ++s2) {
        unsigned int* wp = wnp + (size_t)(b * 2 + s2) * 25 * HW + tile * 256 + tid;
        #pragma unroll
        for (int k = 0; k < 25; ++k) {
            unsigned short lo = __builtin_bit_cast(unsigned short, lrow[(2 * s2) * 25 + k]);
            unsigned short hi = __builtin_bit_cast(unsigned short, lrow[(2 * s2 + 1) * 25 + k]);
            wp[(size_t)k * HW] = (unsigned int)lo | ((unsigned int)hi << 16);  // 256B/wave
        }
    }
}

// ---------- kernel A: softmax + gather. tile 16x16, 512 blocks, 512 thr ----------
__global__ __launch_bounds__(512, 4)
void carafe_apply(const __bf16* __restrict__ xt, const unsigned int* __restrict__ wnp,
                  float* __restrict__ out) {
    __shared__ __bf16 lx[400 * 68];   // 54,400 B; rows = 20x20 halo, cols = 64 ch pad 68

    const int tid = threadIdx.x;
    const int b = blockIdx.x & 7, tile = blockIdx.x >> 3;    // XCD-pin batch
    const int h0 = (tile >> 3) << 4, w0 = (tile & 7) << 4;

    // ---- T14 issue: halo loads into regs (fly over the logit loads + softmax)
    const int l8 = tid & 7, pg = tid >> 3;   // 64 pos-groups
    bf16x8 hv[7];
    #pragma unroll
    for (int it = 0; it < 7; ++it) {
        int pos = it * 64 + pg;
        bf16x8 v = {};
        if (pos < 400) {
            int r = pos / 20, q = pos % 20;
            int hy = h0 - 2 + r, wx = w0 - 2 + q;
            if (hy >= 0 && hy < 128 && wx >= 0 && wx < 128)
                v = *(const bf16x8*)(xt + ((size_t)b * HW + hy * 128 + wx) * 64 + l8 * 8);
        }
        hv[it] = v;
    }

    // ---- load 25 packed logit dwords (2 groups), softmax in f32 under load shadow
    const int pix = tid & 255, sgrp = tid >> 8;
    const int py = pix >> 4, px = pix & 15;
    const int h = h0 + py, w = w0 + px;
    float wt_[50];
    {
        const unsigned int* wp = wnp + (size_t)(b * 2 + sgrp) * 25 * HW + tile * 256 + pix;
        #pragma unroll
        for (int k = 0; k < 25; ++k) {
            unsigned int u = wp[(size_t)k * HW];
            wt_[k]      = (float)__builtin_bit_cast(_Float16, (unsigned short)(u & 0xffffu));
            wt_[25 + k] = (float)__builtin_bit_cast(_Float16, (unsigned short)(u >> 16));
        }
        #pragma unroll
        for (int g = 0; g < 2; ++g) {
            float* v = wt_ + g * 25;
            float mx = v[0];
            #pragma unroll
            for (int k = 1; k < 25; ++k) mx = fmaxf(mx, v[k]);
            float s = 0.f;
            #pragma unroll
            for (int k = 0; k < 25; ++k) { v[k] = __expf(v[k] - mx); s += v[k]; }
            float inv = 1.f / s;
            #pragma unroll
            for (int k = 0; k < 25; ++k) v[k] *= inv;
        }
    }

    // ---- T14 write: stage halo to LDS
    #pragma unroll
    for (int it = 0; it < 7; ++it) {
        int pos = it * 64 + pg;
        if (pos < 400) {
            bf16x4 vlo = {hv[it][0], hv[it][1], hv[it][2], hv[it][3]};
            bf16x4 vhi = {hv[it][4], hv[it][5], hv[it][6], hv[it][7]};
            *(bf16x4*)(lx + pos * 68 + l8 * 8)     = vlo;
            *(bf16x4*)(lx + pos * 68 + l8 * 8 + 4) = vhi;
        }
    }
    __syncthreads();

    // ---- 5x5 weighted gather from LDS + pixel shuffle (NT stores)
    float* ob = out + (size_t)b * 256 * HW;
    #pragma unroll 2
    for (int cq = 0; cq < 16; ++cq) {          // channels c = 4*cq .. 4*cq+3
        f32x2 a0 = {0.f, 0.f}, a1 = {0.f, 0.f}, a2 = {0.f, 0.f}, a3 = {0.f, 0.f};
        #pragma unroll
        for (int ki = 0; ki < 5; ++ki) {
            const int rowbase = (py + ki) * 20 + px;
            #pragma unroll
            for (int kj = 0; kj < 5; ++kj) {
                uint2 u = *(const uint2*)(lx + (rowbase + kj) * 68 + cq * 4);
                f32x2 xlo = { __uint_as_float(u.x << 16), __uint_as_float(u.x & 0xffff0000u) };
                f32x2 xhi = { __uint_as_float(u.y << 16), __uint_as_float(u.y & 0xffff0000u) };
                float wA = wt_[ki * 5 + kj];
                float wB = wt_[25 + ki * 5 + kj];
                a0 += xlo * wA;
                a1 += xhi * wA;
                a2 += xlo * wB;
                a3 += xhi * wB;
            }
        }
        // ch C = s*64 + 4cq + d -> plane q = s*16+cq, (r1,r2) = (d>>1, d&1); s = 2sgrp{+1}
        size_t base0 = ((size_t)(sgrp * 32 + cq) * 256 + 2 * h) * 256 + 2 * w;
        size_t base1 = base0 + (size_t)16 * 256 * 256;
        __builtin_nontemporal_store(a0, (f32x2*)(ob + base0));
        __builtin_nontemporal_store(a1, (f32x2*)(ob + base0 + 256));
        __builtin_nontemporal_store(a2, (f32x2*)(ob + base1));
        __builtin_nontemporal_store(a3, (f32x2*)(ob + base1 + 256));
    }
}

extern "C" void kernel_launch(void* const* d_in, const int* in_sizes, int n_in,
                              void* d_out, int out_size, void* d_ws, size_t ws_size,
                              hipStream_t stream) {
    const float* x  = (const float*)d_in[0];   // [8][64][128][128]
    const float* wc = (const float*)d_in[1];   // [48][64]
    const float* bc = (const float*)d_in[2];   // [48]
    const float* we = (const float*)d_in[3];   // [100][48][3][3]
    const float* be = (const float*)d_in[4];   // [100]
    float* out = (float*)d_out;                // [8][64][256][256]

    // ws: xt 16,777,216 | y1 25,165,824 | wte 114,688 | wcb 6,144 | wnp 26,214,400
    __bf16*       xt  = (__bf16*)d_ws;
    __bf16*       y1g = (__bf16*)((char*)d_ws + 16777216);
    __bf16*       wte = (__bf16*)((char*)d_ws + 41943040);
    __bf16*       wcb = (__bf16*)((char*)d_ws + 41943040 + 114688);
    unsigned int* wnp = (unsigned int*)((char*)d_ws + 41943040 + 114688 + 6144);

    prep_w<<<236, 256, 0, stream>>>(we, wc, wte, wcb);
    prep_xty1<<<512, 256, 0, stream>>>(x, wcb, bc, xt, y1g);
    carafe_weights<<<512, 256, 0, stream>>>(y1g, wte, be, wnp);
    carafe_apply<<<512, 512, 0, stream>>>(xt, wnp, out);
}

// Round 16
// 91.965 us; speedup vs baseline: 2.1275x; 2.1275x over previous
//
#include <hip/hip_runtime.h>

#define HW 16384   // 128*128

typedef __bf16 bf16x8 __attribute__((ext_vector_type(8)));
typedef __bf16 bf16x4 __attribute__((ext_vector_type(4)));
typedef float  f32x4  __attribute__((ext_vector_type(4)));
typedef float  f32x2  __attribute__((ext_vector_type(2)));

// ---------- prep 0: w_t[128][448] bf16 (k = t*48+m, zero-pad), wc_bf[48][64] ----------
__global__ __launch_bounds__(256)
void prep_w(const float* __restrict__ we, const float* __restrict__ wc,
            __bf16* __restrict__ wt, __bf16* __restrict__ wcb) {
    int idx = blockIdx.x * 256 + threadIdx.x;
    if (idx < 128 * 448) {
        int e = idx / 448, k = idx % 448;
        float v = 0.f;
        if (e < 100 && k < 432) {
            int t = k / 48, m = k % 48;
            v = we[(e * 48 + m) * 9 + t];
        }
        wt[idx] = (__bf16)v;
    } else {
        idx -= 128 * 448;
        if (idx < 48 * 64) wcb[idx] = (__bf16)wc[idx];
    }
}

// ---------- prep 1: x -> xt [b][pos][64] bf16  AND  y1 [b][pos][48] bf16 ----------
// y1 = relu(conv1x1(x)+bc) via MFMA on the in-LDS f32 tile (swapped operands).
__global__ __launch_bounds__(256, 2)
void prep_xty1(const float* __restrict__ x, const __bf16* __restrict__ wcb,
               const float* __restrict__ bc,
               __bf16* __restrict__ xt, __bf16* __restrict__ y1o) {
    __shared__ __align__(16) float lds[256 * 65];      // 66,560 B
    __bf16* y1s = (__bf16*)lds;                        // [256][56] union (after barrier)

    const int b = blockIdx.x & 7, chunk = blockIdx.x >> 3;   // XCD-pin batch
    const int t = threadIdx.x;
    const int lane = t & 63, wv = t >> 6;
    const int lgp = lane >> 4, lr = lane & 15;
    const int pos0 = chunk * 256;

    // ---- phase 1: coalesced f32 load + LDS transpose
    const float* xb = x + (size_t)b * 64 * HW + pos0;
    for (int c = 0; c < 64; ++c)
        lds[t * 65 + c] = xb[(size_t)c * HW + t];
    __syncthreads();

    // ---- phase 2: xt stores (wave-contiguous) + y1 A-fragments into regs
    {
        const int q = t & 3, pp = t >> 2;
        #pragma unroll
        for (int it = 0; it < 4; ++it) {
            int pos = it * 64 + pp;
            __bf16* o = xt + ((size_t)b * HW + pos0 + pos) * 64 + q * 16;
            bf16x8 v0, v1;
            #pragma unroll
            for (int e = 0; e < 8; ++e) {
                v0[e] = (__bf16)lds[pos * 65 + q * 16 + e];
                v1[e] = (__bf16)lds[pos * 65 + q * 16 + 8 + e];
            }
            *(bf16x8*)o       = v0;
            *(bf16x8*)(o + 8) = v1;
        }
    }
    bf16x8 af[4][2];                       // 4 M-tiles x 2 K-chunks, lane pixel = lr
    #pragma unroll
    for (int i = 0; i < 4; ++i) {
        int pix = (wv * 4 + i) * 16 + lr;
        #pragma unroll
        for (int kc = 0; kc < 2; ++kc)
            #pragma unroll
            for (int e = 0; e < 8; ++e)
                af[i][kc][e] = (__bf16)lds[pix * 65 + kc * 32 + lgp * 8 + e];
    }
    __syncthreads();

    // ---- phase 3: MFMA conv1x1 (swapped: D col = own pixel) -> y1s spill
    {
        bf16x8 bw[3][2];
        f32x4 bias4[3];
        #pragma unroll
        for (int nt = 0; nt < 3; ++nt) {
            bias4[nt] = *(const f32x4*)(bc + nt * 16 + lgp * 4);
            #pragma unroll
            for (int kc = 0; kc < 2; ++kc)
                bw[nt][kc] = *(const bf16x8*)(wcb + (nt * 16 + lr) * 64 + kc * 32 + lgp * 8);
        }
        #pragma unroll
        for (int i = 0; i < 4; ++i) {
            int pix = (wv * 4 + i) * 16 + lr;
            #pragma unroll
            for (int nt = 0; nt < 3; ++nt) {
                f32x4 cc = bias4[nt];
                cc = __builtin_amdgcn_mfma_f32_16x16x32_bf16(bw[nt][0], af[i][0], cc, 0, 0, 0);
                cc = __builtin_amdgcn_mfma_f32_16x16x32_bf16(bw[nt][1], af[i][1], cc, 0, 0, 0);
                bf16x4 o4;
                #pragma unroll
                for (int r = 0; r < 4; ++r) o4[r] = (__bf16)fmaxf(cc[r], 0.f);
                *(bf16x4*)(y1s + pix * 56 + nt * 16 + lgp * 4) = o4;
            }
        }
    }
    __syncthreads();

    // ---- phase 4: y1s -> global [256][48], wave-contiguous 16B stores
    __bf16* yo = y1o + (size_t)(b * HW + pos0) * 48;
    #pragma unroll
    for (int i = 0; i < 6; ++i) {
        int c = i * 256 + t;                     // 1536 chunks of 8 halfwords
        int pix = (c * 10923) >> 16;             // c / 6
        int mc  = c - pix * 6;
        bf16x8 v = *(bf16x8*)(y1s + pix * 56 + mc * 8);
        *(bf16x8*)(yo + (size_t)c * 8) = v;
    }
}

// ---------- kernel W: y1-halo stage -> conv3x3(MFMA) -> packed f16x2 logits ----------
// 256 thr, tile 16x16, 512 blocks (2/CU). LDS: y1[344][56] -> lgt[256][116]
__global__ __launch_bounds__(256, 2)
void carafe_weights(const __bf16* __restrict__ y1g,
                    const __bf16* __restrict__ wt, const float* __restrict__ be,
                    unsigned int* __restrict__ wnp) {   // [(b*2+s2)*25+k][tile*256+pix]
    __shared__ __align__(16) char smem[59392];
    __bf16*    y1  = (__bf16*)smem;    // [344][56]
    _Float16*  lgt = (_Float16*)smem;  // [256][116]

    const int tid = threadIdx.x;
    const int lane = tid & 63, wv = tid >> 6;
    const int lgp = lane >> 4, lr = lane & 15;
    const int b = blockIdx.x & 7, tile = blockIdx.x >> 3;    // XCD-pin batch
    const int h0 = (tile >> 3) << 4, w0 = (tile & 7) << 4;

    // ===== stage y1 halo (18x18 pos x 48 ch), zero outside image
    const __bf16* y1b = y1g + (size_t)b * HW * 48;
    #pragma unroll
    for (int it = 0; it < 8; ++it) {
        int id = it * 256 + tid;                 // (hr, wc, mc): 18*18*6 = 1944
        if (id < 1944) {
            int hr  = (id * 607) >> 16;          // id / 108
            int rem = id - hr * 108;
            int wc  = (rem * 10923) >> 16;       // rem / 6
            int mc  = rem - wc * 6;
            int hy = h0 - 1 + hr, wx = w0 - 1 + wc;
            bf16x8 v = {};
            if (hy >= 0 && hy < 128 && wx >= 0 && wx < 128)
                v = *(const bf16x8*)(y1b + (size_t)(hy * 128 + wx) * 48 + mc * 8);
            *(bf16x8*)(y1 + (hr * 18 + wc) * 56 + mc * 8) = v;
        }
    }
    for (int i = tid; i < 1120; i += 256)
        y1[324 * 56 + i] = (__bf16)0.f;          // rows 324..343 (K-pad t=9 reads)
    __syncthreads();

    // ===== P2: logits[256px][112] = Ycol[px][432] * W[432][112], 4 waves x 4 px-tiles
    f32x4 acc[4][7];
    #pragma unroll
    for (int ot = 0; ot < 7; ++ot) {
        int o_ = ot * 16 + lr;
        float bz = (o_ < 100) ? be[o_] : 0.f;
        #pragma unroll
        for (int i = 0; i < 4; ++i) acc[i][ot] = {bz, bz, bz, bz};
    }
    const int ptg0 = wv * 4;

    auto ldA = [&](bf16x8 A[4], int kc) {
        int Kb = kc * 32 + lgp * 8;
        int t  = (Kb * 683) >> 15;  int m0 = Kb - t * 48;   // k = t*48+m
        int ty = (t * 11) >> 5;     int tx = t - ty * 3;
        int base = ty * 18 + lr + tx;
        #pragma unroll
        for (int i = 0; i < 4; ++i)
            A[i] = *(const bf16x8*)(y1 + ((ptg0 + i) * 18 + base) * 56 + m0);
    };
    auto ldB = [&](bf16x8 B[7], int kc) {
        #pragma unroll
        for (int j = 0; j < 7; ++j)
            B[j] = *(const bf16x8*)(wt + (j * 16 + lr) * 448 + kc * 32 + lgp * 8);
    };
    auto mm = [&](bf16x8 A[4], bf16x8 B[7]) {
        #pragma unroll
        for (int i = 0; i < 4; ++i)
            #pragma unroll
            for (int j = 0; j < 7; ++j)
                acc[i][j] = __builtin_amdgcn_mfma_f32_16x16x32_bf16(A[i], B[j], acc[i][j], 0, 0, 0);
    };

    bf16x8 A0[4], B0[7], A1[4], B1[7];
    ldA(A0, 0); ldB(B0, 0);
    #pragma unroll
    for (int kc = 0; kc < 14; kc += 2) {
        if (kc + 1 < 14) { ldA(A1, kc + 1); ldB(B1, kc + 1); }
        mm(A0, B0);
        if (kc + 2 < 14) { ldA(A0, kc + 2); ldB(B0, kc + 2); }
        if (kc + 1 < 14) mm(A1, B1);
    }
    __syncthreads();   // y1 dead

    // ===== P3: spill logits to LDS [256][116] fp16
    #pragma unroll
    for (int i = 0; i < 4; ++i)
        #pragma unroll
        for (int j = 0; j < 7; ++j) {
            int o_ = j * 16 + lr;
            #pragma unroll
            for (int r = 0; r < 4; ++r) {
                int p = (ptg0 + i) * 16 + lgp * 4 + r;
                lgt[p * 116 + o_] = (_Float16)acc[i][j][r];
            }
        }
    __syncthreads();

    // ===== P4: pack f16x2 logit pairs, tile-local contiguous store
    const _Float16* lrow = lgt + tid * 116;
    #pragma unroll
    for (int s2 = 0; s2 < 2; ++s2) {
        unsigned int* wp = wnp + (size_t)(b * 2 + s2) * 25 * HW + tile * 256 + tid;
        #pragma unroll
        for (int k = 0; k < 25; ++k) {
            unsigned short lo = __builtin_bit_cast(unsigned short, lrow[(2 * s2) * 25 + k]);
            unsigned short hi = __builtin_bit_cast(unsigned short, lrow[(2 * s2 + 1) * 25 + k]);
            wp[(size_t)k * HW] = (unsigned int)lo | ((unsigned int)hi << 16);  // 256B/wave
        }
    }
}

// ---------- kernel A: softmax + gather. tile 16x16, 512 blocks, 512 thr ----------
// __launch_bounds__(512,2): VGPR cap 256 -> the ~100-reg working set (wt_[50]+hv[7])
// fits with ZERO spill (R15: (512,4) forced VGPR=64 -> scratch -> 163us).
// LDS 54.4KB caps at 2 blocks/CU anyway, so occupancy is unchanged.
__global__ __launch_bounds__(512, 2)
void carafe_apply(const __bf16* __restrict__ xt, const unsigned int* __restrict__ wnp,
                  float* __restrict__ out) {
    __shared__ __bf16 lx[400 * 68];   // 54,400 B; rows = 20x20 halo, cols = 64 ch pad 68

    const int tid = threadIdx.x;
    const int b = blockIdx.x & 7, tile = blockIdx.x >> 3;    // XCD-pin batch
    const int h0 = (tile >> 3) << 4, w0 = (tile & 7) << 4;

    // ---- T14 issue: halo loads into regs (fly over the logit loads + softmax)
    const int l8 = tid & 7, pg = tid >> 3;   // 64 pos-groups
    bf16x8 hv[7];
    #pragma unroll
    for (int it = 0; it < 7; ++it) {
        int pos = it * 64 + pg;
        bf16x8 v = {};
        if (pos < 400) {
            int r = pos / 20, q = pos % 20;
            int hy = h0 - 2 + r, wx = w0 - 2 + q;
            if (hy >= 0 && hy < 128 && wx >= 0 && wx < 128)
                v = *(const bf16x8*)(xt + ((size_t)b * HW + hy * 128 + wx) * 64 + l8 * 8);
        }
        hv[it] = v;
    }

    // ---- load 25 packed logit dwords (2 groups), softmax in f32 under load shadow
    const int pix = tid & 255, sgrp = tid >> 8;
    const int py = pix >> 4, px = pix & 15;
    const int h = h0 + py, w = w0 + px;
    float wt_[50];
    {
        const unsigned int* wp = wnp + (size_t)(b * 2 + sgrp) * 25 * HW + tile * 256 + pix;
        #pragma unroll
        for (int k = 0; k < 25; ++k) {
            unsigned int u = wp[(size_t)k * HW];
            wt_[k]      = (float)__builtin_bit_cast(_Float16, (unsigned short)(u & 0xffffu));
            wt_[25 + k] = (float)__builtin_bit_cast(_Float16, (unsigned short)(u >> 16));
        }
        #pragma unroll
        for (int g = 0; g < 2; ++g) {
            float* v = wt_ + g * 25;
            float mx = v[0];
            #pragma unroll
            for (int k = 1; k < 25; ++k) mx = fmaxf(mx, v[k]);
            float s = 0.f;
            #pragma unroll
            for (int k = 0; k < 25; ++k) { v[k] = __expf(v[k] - mx); s += v[k]; }
            float inv = 1.f / s;
            #pragma unroll
            for (int k = 0; k < 25; ++k) v[k] *= inv;
        }
    }

    // ---- T14 write: stage halo to LDS
    #pragma unroll
    for (int it = 0; it < 7; ++it) {
        int pos = it * 64 + pg;
        if (pos < 400) {
            bf16x4 vlo = {hv[it][0], hv[it][1], hv[it][2], hv[it][3]};
            bf16x4 vhi = {hv[it][4], hv[it][5], hv[it][6], hv[it][7]};
            *(bf16x4*)(lx + pos * 68 + l8 * 8)     = vlo;
            *(bf16x4*)(lx + pos * 68 + l8 * 8 + 4) = vhi;
        }
    }
    __syncthreads();

    // ---- 5x5 weighted gather from LDS + pixel shuffle (NT stores)
    float* ob = out + (size_t)b * 256 * HW;
    #pragma unroll 1
    for (int cq = 0; cq < 16; ++cq) {          // channels c = 4*cq .. 4*cq+3
        f32x2 a0 = {0.f, 0.f}, a1 = {0.f, 0.f}, a2 = {0.f, 0.f}, a3 = {0.f, 0.f};
        #pragma unroll
        for (int ki = 0; ki < 5; ++ki) {
            const int rowbase = (py + ki) * 20 + px;
            #pragma unroll
            for (int kj = 0; kj < 5; ++kj) {
                uint2 u = *(const uint2*)(lx + (rowbase + kj) * 68 + cq * 4);
                f32x2 xlo = { __uint_as_float(u.x << 16), __uint_as_float(u.x & 0xffff0000u) };
                f32x2 xhi = { __uint_as_float(u.y << 16), __uint_as_float(u.y & 0xffff0000u) };
                float wA = wt_[ki * 5 + kj];
                float wB = wt_[25 + ki * 5 + kj];
                a0 += xlo * wA;
                a1 += xhi * wA;
                a2 += xlo * wB;
                a3 += xhi * wB;
            }
        }
        // ch C = s*64 + 4cq + d -> plane q = s*16+cq, (r1,r2) = (d>>1, d&1); s = 2sgrp{+1}
        size_t base0 = ((size_t)(sgrp * 32 + cq) * 256 + 2 * h) * 256 + 2 * w;
        size_t base1 = base0 + (size_t)16 * 256 * 256;
        __builtin_nontemporal_store(a0, (f32x2*)(ob + base0));
        __builtin_nontemporal_store(a1, (f32x2*)(ob + base0 + 256));
        __builtin_nontemporal_store(a2, (f32x2*)(ob + base1));
        __builtin_nontemporal_store(a3, (f32x2*)(ob + base1 + 256));
    }
}

extern "C" void kernel_launch(void* const* d_in, const int* in_sizes, int n_in,
                              void* d_out, int out_size, void* d_ws, size_t ws_size,
                              hipStream_t stream) {
    const float* x  = (const float*)d_in[0];   // [8][64][128][128]
    const float* wc = (const float*)d_in[1];   // [48][64]
    const float* bc = (const float*)d_in[2];   // [48]
    const float* we = (const float*)d_in[3];   // [100][48][3][3]
    const float* be = (const float*)d_in[4];   // [100]
    float* out = (float*)d_out;                // [8][64][256][256]

    // ws: xt 16,777,216 | y1 25,165,824 | wte 114,688 | wcb 6,144 | wnp 26,214,400
    __bf16*       xt  = (__bf16*)d_ws;
    __bf16*       y1g = (__bf16*)((char*)d_ws + 16777216);
    __bf16*       wte = (__bf16*)((char*)d_ws + 41943040);
    __bf16*       wcb = (__bf16*)((char*)d_ws + 41943040 + 114688);
    unsigned int* wnp = (unsigned int*)((char*)d_ws + 41943040 + 114688 + 6144);

    prep_w<<<236, 256, 0, stream>>>(we, wc, wte, wcb);
    prep_xty1<<<512, 256, 0, stream>>>(x, wcb, bc, xt, y1g);
    carafe_weights<<<512, 256, 0, stream>>>(y1g, wte, be, wnp);
    carafe_apply<<<512, 512, 0, stream>>>(xt, wnp, out);
}

// Round 17
// 79.750 us; speedup vs baseline: 2.4533x; 1.1532x over previous
//
#include <hip/hip_runtime.h>

#define HW 16384   // 128*128

typedef __bf16 bf16x8 __attribute__((ext_vector_type(8)));
typedef __bf16 bf16x4 __attribute__((ext_vector_type(4)));
typedef float  f32x4  __attribute__((ext_vector_type(4)));
typedef float  f32x2  __attribute__((ext_vector_type(2)));

// ---------- prep 0: w_t[128][448] bf16 (k = t*48+m, zero-pad), wc_bf[48][64] ----------
__global__ __launch_bounds__(256)
void prep_w(const float* __restrict__ we, const float* __restrict__ wc,
            __bf16* __restrict__ wt, __bf16* __restrict__ wcb) {
    int idx = blockIdx.x * 256 + threadIdx.x;
    if (idx < 128 * 448) {
        int e = idx / 448, k = idx % 448;
        float v = 0.f;
        if (e < 100 && k < 432) {
            int t = k / 48, m = k % 48;
            v = we[(e * 48 + m) * 9 + t];
        }
        wt[idx] = (__bf16)v;
    } else {
        idx -= 128 * 448;
        if (idx < 48 * 64) wcb[idx] = (__bf16)wc[idx];
    }
}

// ---------- prep 1: x -> xt [b][pos][64] bf16  AND  y1 [b][pos][48] bf16 ----------
__global__ __launch_bounds__(256, 2)
void prep_xty1(const float* __restrict__ x, const __bf16* __restrict__ wcb,
               const float* __restrict__ bc,
               __bf16* __restrict__ xt, __bf16* __restrict__ y1o) {
    __shared__ __align__(16) float lds[256 * 65];      // 66,560 B
    __bf16* y1s = (__bf16*)lds;                        // [256][56] union (after barrier)

    const int b = blockIdx.x & 7, chunk = blockIdx.x >> 3;   // XCD-pin batch
    const int t = threadIdx.x;
    const int lane = t & 63, wv = t >> 6;
    const int lgp = lane >> 4, lr = lane & 15;
    const int pos0 = chunk * 256;

    const float* xb = x + (size_t)b * 64 * HW + pos0;
    for (int c = 0; c < 64; ++c)
        lds[t * 65 + c] = xb[(size_t)c * HW + t];
    __syncthreads();

    {   // xt stores (wave-contiguous 2KB)
        const int q = t & 3, pp = t >> 2;
        #pragma unroll
        for (int it = 0; it < 4; ++it) {
            int pos = it * 64 + pp;
            __bf16* o = xt + ((size_t)b * HW + pos0 + pos) * 64 + q * 16;
            bf16x8 v0, v1;
            #pragma unroll
            for (int e = 0; e < 8; ++e) {
                v0[e] = (__bf16)lds[pos * 65 + q * 16 + e];
                v1[e] = (__bf16)lds[pos * 65 + q * 16 + 8 + e];
            }
            *(bf16x8*)o       = v0;
            *(bf16x8*)(o + 8) = v1;
        }
    }
    bf16x8 af[4][2];                       // A-fragments, lane pixel = lr
    #pragma unroll
    for (int i = 0; i < 4; ++i) {
        int pix = (wv * 4 + i) * 16 + lr;
        #pragma unroll
        for (int kc = 0; kc < 2; ++kc)
            #pragma unroll
            for (int e = 0; e < 8; ++e)
                af[i][kc][e] = (__bf16)lds[pix * 65 + kc * 32 + lgp * 8 + e];
    }
    __syncthreads();

    {   // conv1x1 MFMA (swapped: D col = own pixel) -> y1s
        bf16x8 bw[3][2];
        f32x4 bias4[3];
        #pragma unroll
        for (int nt = 0; nt < 3; ++nt) {
            bias4[nt] = *(const f32x4*)(bc + nt * 16 + lgp * 4);
            #pragma unroll
            for (int kc = 0; kc < 2; ++kc)
                bw[nt][kc] = *(const bf16x8*)(wcb + (nt * 16 + lr) * 64 + kc * 32 + lgp * 8);
        }
        #pragma unroll
        for (int i = 0; i < 4; ++i) {
            int pix = (wv * 4 + i) * 16 + lr;
            #pragma unroll
            for (int nt = 0; nt < 3; ++nt) {
                f32x4 cc = bias4[nt];
                cc = __builtin_amdgcn_mfma_f32_16x16x32_bf16(bw[nt][0], af[i][0], cc, 0, 0, 0);
                cc = __builtin_amdgcn_mfma_f32_16x16x32_bf16(bw[nt][1], af[i][1], cc, 0, 0, 0);
                bf16x4 o4;
                #pragma unroll
                for (int r = 0; r < 4; ++r) o4[r] = (__bf16)fmaxf(cc[r], 0.f);
                *(bf16x4*)(y1s + pix * 56 + nt * 16 + lgp * 4) = o4;
            }
        }
    }
    __syncthreads();

    __bf16* yo = y1o + (size_t)(b * HW + pos0) * 48;
    #pragma unroll
    for (int i = 0; i < 6; ++i) {
        int c = i * 256 + t;                     // 1536 chunks of 8 halfwords
        int pix = (c * 10923) >> 16;             // c / 6
        int mc  = c - pix * 6;
        bf16x8 v = *(bf16x8*)(y1s + pix * 56 + mc * 8);
        *(bf16x8*)(yo + (size_t)c * 8) = v;
    }
}

// ---------- fused W+A: y1-halo -> conv3x3(MFMA) -> softmax -> gather -> out ----------
// 256 thr, tile 16x16, 512 blocks, (256,2) -> 2 blocks/CU, VGPR cap 256 (no spill).
// LDS union: y1[344][56] 38.5K -> lgt[256][118] 60.4K -> lx[400][68] 54.4K
__global__ __launch_bounds__(256, 2)
void carafe_wa(const __bf16* __restrict__ xt, const __bf16* __restrict__ y1g,
               const __bf16* __restrict__ wt, const float* __restrict__ be,
               float* __restrict__ out) {
    __shared__ __align__(16) char smem[60416];
    __bf16*    y1  = (__bf16*)smem;    // [344][56]
    _Float16*  lgt = (_Float16*)smem;  // [256][118] (odd-dword stride: conflict-free)
    __bf16*    lx  = (__bf16*)smem;    // [400][68]

    const int tid = threadIdx.x;
    const int lane = tid & 63, wv = tid >> 6;
    const int lgp = lane >> 4, lr = lane & 15;
    const int b = blockIdx.x & 7, tile = blockIdx.x >> 3;    // XCD-pin batch
    const int h0 = (tile >> 3) << 4, w0 = (tile & 7) << 4;

    // ===== stage y1 halo (18x18 pos x 48 ch), zero outside image
    const __bf16* y1b = y1g + (size_t)b * HW * 48;
    #pragma unroll
    for (int it = 0; it < 8; ++it) {
        int id = it * 256 + tid;                 // (hr, wc, mc): 18*18*6 = 1944
        if (id < 1944) {
            int hr  = (id * 607) >> 16;          // id / 108
            int rem = id - hr * 108;
            int wc  = (rem * 10923) >> 16;       // rem / 6
            int mc  = rem - wc * 6;
            int hy = h0 - 1 + hr, wx = w0 - 1 + wc;
            bf16x8 v = {};
            if (hy >= 0 && hy < 128 && wx >= 0 && wx < 128)
                v = *(const bf16x8*)(y1b + (size_t)(hy * 128 + wx) * 48 + mc * 8);
            *(bf16x8*)(y1 + (hr * 18 + wc) * 56 + mc * 8) = v;
        }
    }
    for (int i = tid; i < 1120; i += 256)
        y1[324 * 56 + i] = (__bf16)0.f;          // rows 324..343 (K-pad t=9 reads)
    __syncthreads();

    // ===== P2: logits[256px][112] = Ycol[px][432] * W[432][112]
    f32x4 acc[4][7];
    #pragma unroll
    for (int ot = 0; ot < 7; ++ot) {
        int o_ = ot * 16 + lr;
        float bz = (o_ < 100) ? be[o_] : 0.f;
        #pragma unroll
        for (int i = 0; i < 4; ++i) acc[i][ot] = {bz, bz, bz, bz};
    }
    const int ptg0 = wv * 4;

    auto ldA = [&](bf16x8 A[4], int kc) {
        int Kb = kc * 32 + lgp * 8;
        int t  = (Kb * 683) >> 15;  int m0 = Kb - t * 48;   // k = t*48+m
        int ty = (t * 11) >> 5;     int tx = t - ty * 3;
        int base = ty * 18 + lr + tx;
        #pragma unroll
        for (int i = 0; i < 4; ++i)
            A[i] = *(const bf16x8*)(y1 + ((ptg0 + i) * 18 + base) * 56 + m0);
    };
    auto ldB = [&](bf16x8 B[7], int kc) {
        #pragma unroll
        for (int j = 0; j < 7; ++j)
            B[j] = *(const bf16x8*)(wt + (j * 16 + lr) * 448 + kc * 32 + lgp * 8);
    };
    auto mm = [&](bf16x8 A[4], bf16x8 B[7]) {
        #pragma unroll
        for (int i = 0; i < 4; ++i)
            #pragma unroll
            for (int j = 0; j < 7; ++j)
                acc[i][j] = __builtin_amdgcn_mfma_f32_16x16x32_bf16(A[i], B[j], acc[i][j], 0, 0, 0);
    };

    bf16x8 A0[4], B0[7], A1[4], B1[7];
    ldA(A0, 0); ldB(B0, 0);
    #pragma unroll
    for (int kc = 0; kc < 14; kc += 2) {
        if (kc + 1 < 14) { ldA(A1, kc + 1); ldB(B1, kc + 1); }
        mm(A0, B0);
        if (kc + 2 < 14) { ldA(A0, kc + 2); ldB(B0, kc + 2); }
        if (kc + 1 < 14) mm(A1, B1);
    }
    __syncthreads();   // y1 dead

    // ===== spill logits to LDS [256][118] fp16
    #pragma unroll
    for (int i = 0; i < 4; ++i)
        #pragma unroll
        for (int j = 0; j < 7; ++j) {
            int o_ = j * 16 + lr;
            #pragma unroll
            for (int r = 0; r < 4; ++r) {
                int p = (ptg0 + i) * 16 + lgp * 4 + r;
                lgt[p * 118 + o_] = (_Float16)acc[i][j][r];
            }
        }

    // ===== T14: issue x-halo loads NOW (latency hides under barrier + softmax)
    bf16x8 hv[13];
    #pragma unroll
    for (int it = 0; it < 13; ++it) {
        int id = it * 256 + tid;                 // 400 pos x 8 ch-chunks = 3200
        bf16x8 v = {};
        if (id < 3200) {
            int pos = id >> 3, l8 = id & 7;
            int r = pos / 20, q = pos % 20;
            int hy = h0 - 2 + r, wx = w0 - 2 + q;
            if (hy >= 0 && hy < 128 && wx >= 0 && wx < 128)
                v = *(const bf16x8*)(xt + ((size_t)b * HW + hy * 128 + wx) * 64 + l8 * 8);
        }
        hv[it] = v;
    }
    __syncthreads();   // lgt visible

    // ===== softmax(25) x4 groups -> wt_[100] regs
    const int py = tid >> 4, px = tid & 15;
    const int h = h0 + py, w = w0 + px;
    float wt_[100];
    {
        const _Float16* lrow = lgt + tid * 118;
        #pragma unroll
        for (int g = 0; g < 4; ++g) {
            float* v = wt_ + g * 25;
            #pragma unroll
            for (int k = 0; k < 25; ++k) v[k] = (float)lrow[g * 25 + k];
            float mx = v[0];
            #pragma unroll
            for (int k = 1; k < 25; ++k) mx = fmaxf(mx, v[k]);
            float s = 0.f;
            #pragma unroll
            for (int k = 0; k < 25; ++k) { v[k] = __expf(v[k] - mx); s += v[k]; }
            float inv = 1.f / s;
            #pragma unroll
            for (int k = 0; k < 25; ++k) v[k] *= inv;
        }
    }
    __syncthreads();   // all lgt reads done; lx may overwrite

    // ===== stage x halo from in-flight regs
    #pragma unroll
    for (int it = 0; it < 13; ++it) {
        int id = it * 256 + tid;
        if (id < 3200) {
            int pos = id >> 3, l8 = id & 7;
            bf16x4 vlo = {hv[it][0], hv[it][1], hv[it][2], hv[it][3]};
            bf16x4 vhi = {hv[it][4], hv[it][5], hv[it][6], hv[it][7]};
            *(bf16x4*)(lx + pos * 68 + l8 * 8)     = vlo;
            *(bf16x4*)(lx + pos * 68 + l8 * 8 + 4) = vhi;
        }
    }
    __syncthreads();

    // ===== 5x5 weighted gather from LDS (1 read feeds 4 groups) + pixel shuffle
    float* ob = out + (size_t)b * 256 * HW;
    #pragma unroll 1
    for (int cq = 0; cq < 16; ++cq) {          // channels c = 4*cq .. 4*cq+3
        f32x2 g0l = {0.f, 0.f}, g0h = {0.f, 0.f}, g1l = {0.f, 0.f}, g1h = {0.f, 0.f};
        f32x2 g2l = {0.f, 0.f}, g2h = {0.f, 0.f}, g3l = {0.f, 0.f}, g3h = {0.f, 0.f};
        #pragma unroll
        for (int ki = 0; ki < 5; ++ki) {
            const int rowbase = (py + ki) * 20 + px;
            #pragma unroll
            for (int kj = 0; kj < 5; ++kj) {
                uint2 u = *(const uint2*)(lx + (rowbase + kj) * 68 + cq * 4);
                f32x2 xlo = { __uint_as_float(u.x << 16), __uint_as_float(u.x & 0xffff0000u) };
                f32x2 xhi = { __uint_as_float(u.y << 16), __uint_as_float(u.y & 0xffff0000u) };
                const int k = ki * 5 + kj;
                float w0_ = wt_[k], w1_ = wt_[25 + k], w2_ = wt_[50 + k], w3_ = wt_[75 + k];
                g0l += xlo * w0_;  g0h += xhi * w0_;
                g1l += xlo * w1_;  g1h += xhi * w1_;
                g2l += xlo * w2_;  g2h += xhi * w2_;
                g3l += xlo * w3_;  g3h += xhi * w3_;
            }
        }
        // ch C = s*64 + 4cq + d -> plane q = s*16+cq, (r1,r2) = (d>>1, d&1)
        const size_t pstride = (size_t)16 * 256 * 256;
        size_t base = ((size_t)cq * 256 + 2 * h) * 256 + 2 * w;
        __builtin_nontemporal_store(g0l, (f32x2*)(ob + base));
        __builtin_nontemporal_store(g0h, (f32x2*)(ob + base + 256));
        __builtin_nontemporal_store(g1l, (f32x2*)(ob + base + pstride));
        __builtin_nontemporal_store(g1h, (f32x2*)(ob + base + pstride + 256));
        __builtin_nontemporal_store(g2l, (f32x2*)(ob + base + 2 * pstride));
        __builtin_nontemporal_store(g2h, (f32x2*)(ob + base + 2 * pstride + 256));
        __builtin_nontemporal_store(g3l, (f32x2*)(ob + base + 3 * pstride));
        __builtin_nontemporal_store(g3h, (f32x2*)(ob + base + 3 * pstride + 256));
    }
}

extern "C" void kernel_launch(void* const* d_in, const int* in_sizes, int n_in,
                              void* d_out, int out_size, void* d_ws, size_t ws_size,
                              hipStream_t stream) {
    const float* x  = (const float*)d_in[0];   // [8][64][128][128]
    const float* wc = (const float*)d_in[1];   // [48][64]
    const float* bc = (const float*)d_in[2];   // [48]
    const float* we = (const float*)d_in[3];   // [100][48][3][3]
    const float* be = (const float*)d_in[4];   // [100]
    float* out = (float*)d_out;                // [8][64][256][256]

    // ws: xt 16,777,216 | y1 25,165,824 | wte 114,688 | wcb 6,144
    __bf16* xt  = (__bf16*)d_ws;
    __bf16* y1g = (__bf16*)((char*)d_ws + 16777216);
    __bf16* wte = (__bf16*)((char*)d_ws + 41943040);
    __bf16* wcb = (__bf16*)((char*)d_ws + 41943040 + 114688);

    prep_w<<<236, 256, 0, stream>>>(we, wc, wte, wcb);
    prep_xty1<<<512, 256, 0, stream>>>(x, wcb, bc, xt, y1g);
    carafe_wa<<<512, 256, 0, stream>>>(xt, y1g, wte, be, out);
}

// Round 18
// 79.633 us; speedup vs baseline: 2.4569x; 1.0015x over previous
//
#include <hip/hip_runtime.h>

#define HW 16384   // 128*128

typedef __bf16 bf16x8 __attribute__((ext_vector_type(8)));
typedef __bf16 bf16x4 __attribute__((ext_vector_type(4)));
typedef float  f32x4  __attribute__((ext_vector_type(4)));
typedef float  f32x2  __attribute__((ext_vector_type(2)));

// ---------- prep 0: w_t[128][448] bf16 (k = t*48+m, zero-pad), wc_bf[48][64] ----------
__global__ __launch_bounds__(256)
void prep_w(const float* __restrict__ we, const float* __restrict__ wc,
            __bf16* __restrict__ wt, __bf16* __restrict__ wcb) {
    int idx = blockIdx.x * 256 + threadIdx.x;
    if (idx < 128 * 448) {
        int e = idx / 448, k = idx % 448;
        float v = 0.f;
        if (e < 100 && k < 432) {
            int t = k / 48, m = k % 48;
            v = we[(e * 48 + m) * 9 + t];
        }
        wt[idx] = (__bf16)v;
    } else {
        idx -= 128 * 448;
        if (idx < 48 * 64) wcb[idx] = (__bf16)wc[idx];
    }
}

// ---------- prep 1: x -> xt [b][pos][64] bf16  AND  y1 [b][pos][48] bf16 ----------
__global__ __launch_bounds__(256, 2)
void prep_xty1(const float* __restrict__ x, const __bf16* __restrict__ wcb,
               const float* __restrict__ bc,
               __bf16* __restrict__ xt, __bf16* __restrict__ y1o) {
    __shared__ __align__(16) float lds[256 * 65];      // 66,560 B
    __bf16* y1s = (__bf16*)lds;                        // [256][56] union (after barrier)

    const int b = blockIdx.x & 7, chunk = blockIdx.x >> 3;   // XCD-pin batch
    const int t = threadIdx.x;
    const int lane = t & 63, wv = t >> 6;
    const int lgp = lane >> 4, lr = lane & 15;
    const int pos0 = chunk * 256;

    const float* xb = x + (size_t)b * 64 * HW + pos0;
    for (int c = 0; c < 64; ++c)
        lds[t * 65 + c] = xb[(size_t)c * HW + t];
    __syncthreads();

    {   // xt stores (wave-contiguous 2KB)
        const int q = t & 3, pp = t >> 2;
        #pragma unroll
        for (int it = 0; it < 4; ++it) {
            int pos = it * 64 + pp;
            __bf16* o = xt + ((size_t)b * HW + pos0 + pos) * 64 + q * 16;
            bf16x8 v0, v1;
            #pragma unroll
            for (int e = 0; e < 8; ++e) {
                v0[e] = (__bf16)lds[pos * 65 + q * 16 + e];
                v1[e] = (__bf16)lds[pos * 65 + q * 16 + 8 + e];
            }
            *(bf16x8*)o       = v0;
            *(bf16x8*)(o + 8) = v1;
        }
    }
    bf16x8 af[4][2];                       // A-fragments, lane pixel = lr
    #pragma unroll
    for (int i = 0; i < 4; ++i) {
        int pix = (wv * 4 + i) * 16 + lr;
        #pragma unroll
        for (int kc = 0; kc < 2; ++kc)
            #pragma unroll
            for (int e = 0; e < 8; ++e)
                af[i][kc][e] = (__bf16)lds[pix * 65 + kc * 32 + lgp * 8 + e];
    }
    __syncthreads();

    {   // conv1x1 MFMA (swapped: D col = own pixel) -> y1s
        bf16x8 bw[3][2];
        f32x4 bias4[3];
        #pragma unroll
        for (int nt = 0; nt < 3; ++nt) {
            bias4[nt] = *(const f32x4*)(bc + nt * 16 + lgp * 4);
            #pragma unroll
            for (int kc = 0; kc < 2; ++kc)
                bw[nt][kc] = *(const bf16x8*)(wcb + (nt * 16 + lr) * 64 + kc * 32 + lgp * 8);
        }
        #pragma unroll
        for (int i = 0; i < 4; ++i) {
            int pix = (wv * 4 + i) * 16 + lr;
            #pragma unroll
            for (int nt = 0; nt < 3; ++nt) {
                f32x4 cc = bias4[nt];
                cc = __builtin_amdgcn_mfma_f32_16x16x32_bf16(bw[nt][0], af[i][0], cc, 0, 0, 0);
                cc = __builtin_amdgcn_mfma_f32_16x16x32_bf16(bw[nt][1], af[i][1], cc, 0, 0, 0);
                bf16x4 o4;
                #pragma unroll
                for (int r = 0; r < 4; ++r) o4[r] = (__bf16)fmaxf(cc[r], 0.f);
                *(bf16x4*)(y1s + pix * 56 + nt * 16 + lgp * 4) = o4;
            }
        }
    }
    __syncthreads();

    __bf16* yo = y1o + (size_t)(b * HW + pos0) * 48;
    #pragma unroll
    for (int i = 0; i < 6; ++i) {
        int c = i * 256 + t;                     // 1536 chunks of 8 halfwords
        int pix = (c * 10923) >> 16;             // c / 6
        int mc  = c - pix * 6;
        bf16x8 v = *(bf16x8*)(y1s + pix * 56 + mc * 8);
        *(bf16x8*)(yo + (size_t)c * 8) = v;
    }
}

// ---------- fused W+A: y1-halo -> conv3x3(MFMA) -> softmax -> gather -> out ----------
// 256 thr, tile 16x16, 512 blocks, (256,2) -> 2 blocks/CU, VGPR cap 256 (no spill).
// LDS union: y1[344][56] 38.5K -> lgt[256][118] 60.4K -> lx[400][68] 54.4K
__global__ __launch_bounds__(256, 2)
void carafe_wa(const __bf16* __restrict__ xt, const __bf16* __restrict__ y1g,
               const __bf16* __restrict__ wt, const float* __restrict__ be,
               float* __restrict__ out) {
    __shared__ __align__(16) char smem[60416];
    __bf16*    y1  = (__bf16*)smem;    // [344][56]
    _Float16*  lgt = (_Float16*)smem;  // [256][118] (odd-dword stride: conflict-free)
    __bf16*    lx  = (__bf16*)smem;    // [400][68]

    const int tid = threadIdx.x;
    const int lane = tid & 63, wv = tid >> 6;
    const int lgp = lane >> 4, lr = lane & 15;
    const int b = blockIdx.x & 7, tile = blockIdx.x >> 3;    // XCD-pin batch
    const int h0 = (tile >> 3) << 4, w0 = (tile & 7) << 4;

    // ===== stage y1 halo (18x18 pos x 48 ch), zero outside image
    const __bf16* y1b = y1g + (size_t)b * HW * 48;
    #pragma unroll
    for (int it = 0; it < 8; ++it) {
        int id = it * 256 + tid;                 // (hr, wc, mc): 18*18*6 = 1944
        if (id < 1944) {
            int hr  = (id * 607) >> 16;          // id / 108
            int rem = id - hr * 108;
            int wc  = (rem * 10923) >> 16;       // rem / 6
            int mc  = rem - wc * 6;
            int hy = h0 - 1 + hr, wx = w0 - 1 + wc;
            bf16x8 v = {};
            if (hy >= 0 && hy < 128 && wx >= 0 && wx < 128)
                v = *(const bf16x8*)(y1b + (size_t)(hy * 128 + wx) * 48 + mc * 8);
            *(bf16x8*)(y1 + (hr * 18 + wc) * 56 + mc * 8) = v;
        }
    }
    for (int i = tid; i < 1120; i += 256)
        y1[324 * 56 + i] = (__bf16)0.f;          // rows 324..343 (K-pad t=9 reads)
    __syncthreads();

    // ===== P2: logits[256px][112] = Ycol[px][432] * W[432][112]
    f32x4 acc[4][7];
    #pragma unroll
    for (int ot = 0; ot < 7; ++ot) {
        int o_ = ot * 16 + lr;
        float bz = (o_ < 100) ? be[o_] : 0.f;
        #pragma unroll
        for (int i = 0; i < 4; ++i) acc[i][ot] = {bz, bz, bz, bz};
    }
    const int ptg0 = wv * 4;

    auto ldA = [&](bf16x8 A[4], int kc) {
        int Kb = kc * 32 + lgp * 8;
        int t  = (Kb * 683) >> 15;  int m0 = Kb - t * 48;   // k = t*48+m
        int ty = (t * 11) >> 5;     int tx = t - ty * 3;
        int base = ty * 18 + lr + tx;
        #pragma unroll
        for (int i = 0; i < 4; ++i)
            A[i] = *(const bf16x8*)(y1 + ((ptg0 + i) * 18 + base) * 56 + m0);
    };
    auto ldB = [&](bf16x8 B[7], int kc) {
        #pragma unroll
        for (int j = 0; j < 7; ++j)
            B[j] = *(const bf16x8*)(wt + (j * 16 + lr) * 448 + kc * 32 + lgp * 8);
    };
    auto mm = [&](bf16x8 A[4], bf16x8 B[7]) {
        #pragma unroll
        for (int i = 0; i < 4; ++i)
            #pragma unroll
            for (int j = 0; j < 7; ++j)
                acc[i][j] = __builtin_amdgcn_mfma_f32_16x16x32_bf16(A[i], B[j], acc[i][j], 0, 0, 0);
    };

    bf16x8 A0[4], B0[7], A1[4], B1[7];
    ldA(A0, 0); ldB(B0, 0);
    #pragma unroll
    for (int kc = 0; kc < 14; kc += 2) {
        if (kc + 1 < 14) { ldA(A1, kc + 1); ldB(B1, kc + 1); }
        mm(A0, B0);
        if (kc + 2 < 14) { ldA(A0, kc + 2); ldB(B0, kc + 2); }
        if (kc + 1 < 14) mm(A1, B1);
    }
    __syncthreads();   // y1 dead

    // ===== spill logits to LDS [256][118] fp16
    #pragma unroll
    for (int i = 0; i < 4; ++i)
        #pragma unroll
        for (int j = 0; j < 7; ++j) {
            int o_ = j * 16 + lr;
            #pragma unroll
            for (int r = 0; r < 4; ++r) {
                int p = (ptg0 + i) * 16 + lgp * 4 + r;
                lgt[p * 118 + o_] = (_Float16)acc[i][j][r];
            }
        }

    // ===== T14: issue x-halo loads NOW (latency hides under barrier + softmax)
    bf16x8 hv[13];
    #pragma unroll
    for (int it = 0; it < 13; ++it) {
        int id = it * 256 + tid;                 // 400 pos x 8 ch-chunks = 3200
        bf16x8 v = {};
        if (id < 3200) {
            int pos = id >> 3, l8 = id & 7;
            int r = pos / 20, q = pos % 20;
            int hy = h0 - 2 + r, wx = w0 - 2 + q;
            if (hy >= 0 && hy < 128 && wx >= 0 && wx < 128)
                v = *(const bf16x8*)(xt + ((size_t)b * HW + hy * 128 + wx) * 64 + l8 * 8);
        }
        hv[it] = v;
    }
    __syncthreads();   // lgt visible

    // ===== softmax(25) x4 groups -> wt_[100] regs
    const int py = tid >> 4, px = tid & 15;
    const int h = h0 + py, w = w0 + px;
    float wt_[100];
    {
        const _Float16* lrow = lgt + tid * 118;
        #pragma unroll
        for (int g = 0; g < 4; ++g) {
            float* v = wt_ + g * 25;
            #pragma unroll
            for (int k = 0; k < 25; ++k) v[k] = (float)lrow[g * 25 + k];
            float mx = v[0];
            #pragma unroll
            for (int k = 1; k < 25; ++k) mx = fmaxf(mx, v[k]);
            float s = 0.f;
            #pragma unroll
            for (int k = 0; k < 25; ++k) { v[k] = __expf(v[k] - mx); s += v[k]; }
            float inv = 1.f / s;
            #pragma unroll
            for (int k = 0; k < 25; ++k) v[k] *= inv;
        }
    }
    __syncthreads();   // all lgt reads done; lx may overwrite

    // ===== stage x halo from in-flight regs
    #pragma unroll
    for (int it = 0; it < 13; ++it) {
        int id = it * 256 + tid;
        if (id < 3200) {
            int pos = id >> 3, l8 = id & 7;
            bf16x4 vlo = {hv[it][0], hv[it][1], hv[it][2], hv[it][3]};
            bf16x4 vhi = {hv[it][4], hv[it][5], hv[it][6], hv[it][7]};
            *(bf16x4*)(lx + pos * 68 + l8 * 8)     = vlo;
            *(bf16x4*)(lx + pos * 68 + l8 * 8 + 4) = vhi;
        }
    }
    __syncthreads();

    // ===== 5x5 weighted gather from LDS (1 read feeds 4 groups) + pixel shuffle
    float* ob = out + (size_t)b * 256 * HW;
    #pragma unroll 1
    for (int cq = 0; cq < 16; ++cq) {          // channels c = 4*cq .. 4*cq+3
        f32x2 g0l = {0.f, 0.f}, g0h = {0.f, 0.f}, g1l = {0.f, 0.f}, g1h = {0.f, 0.f};
        f32x2 g2l = {0.f, 0.f}, g2h = {0.f, 0.f}, g3l = {0.f, 0.f}, g3h = {0.f, 0.f};
        #pragma unroll
        for (int ki = 0; ki < 5; ++ki) {
            const int rowbase = (py + ki) * 20 + px;
            #pragma unroll
            for (int kj = 0; kj < 5; ++kj) {
                uint2 u = *(const uint2*)(lx + (rowbase + kj) * 68 + cq * 4);
                f32x2 xlo = { __uint_as_float(u.x << 16), __uint_as_float(u.x & 0xffff0000u) };
                f32x2 xhi = { __uint_as_float(u.y << 16), __uint_as_float(u.y & 0xffff0000u) };
                const int k = ki * 5 + kj;
                float w0_ = wt_[k], w1_ = wt_[25 + k], w2_ = wt_[50 + k], w3_ = wt_[75 + k];
                g0l += xlo * w0_;  g0h += xhi * w0_;
                g1l += xlo * w1_;  g1h += xhi * w1_;
                g2l += xlo * w2_;  g2h += xhi * w2_;
                g3l += xlo * w3_;  g3h += xhi * w3_;
            }
        }
        // ch C = s*64 + 4cq + d -> plane q = s*16+cq, (r1,r2) = (d>>1, d&1)
        const size_t pstride = (size_t)16 * 256 * 256;
        size_t base = ((size_t)cq * 256 + 2 * h) * 256 + 2 * w;
        __builtin_nontemporal_store(g0l, (f32x2*)(ob + base));
        __builtin_nontemporal_store(g0h, (f32x2*)(ob + base + 256));
        __builtin_nontemporal_store(g1l, (f32x2*)(ob + base + pstride));
        __builtin_nontemporal_store(g1h, (f32x2*)(ob + base + pstride + 256));
        __builtin_nontemporal_store(g2l, (f32x2*)(ob + base + 2 * pstride));
        __builtin_nontemporal_store(g2h, (f32x2*)(ob + base + 2 * pstride + 256));
        __builtin_nontemporal_store(g3l, (f32x2*)(ob + base + 3 * pstride));
        __builtin_nontemporal_store(g3h, (f32x2*)(ob + base + 3 * pstride + 256));
    }
}

extern "C" void kernel_launch(void* const* d_in, const int* in_sizes, int n_in,
                              void* d_out, int out_size, void* d_ws, size_t ws_size,
                              hipStream_t stream) {
    const float* x  = (const float*)d_in[0];   // [8][64][128][128]
    const float* wc = (const float*)d_in[1];   // [48][64]
    const float* bc = (const float*)d_in[2];   // [48]
    const float* we = (const float*)d_in[3];   // [100][48][3][3]
    const float* be = (const float*)d_in[4];   // [100]
    float* out = (float*)d_out;                // [8][64][256][256]

    // ws: xt 16,777,216 | y1 25,165,824 | wte 114,688 | wcb 6,144
    __bf16* xt  = (__bf16*)d_ws;
    __bf16* y1g = (__bf16*)((char*)d_ws + 16777216);
    __bf16* wte = (__bf16*)((char*)d_ws + 41943040);
    __bf16* wcb = (__bf16*)((char*)d_ws + 41943040 + 114688);

    prep_w<<<236, 256, 0, stream>>>(we, wc, wte, wcb);
    prep_xty1<<<512, 256, 0, stream>>>(x, wcb, bc, xt, y1g);
    carafe_wa<<<512, 256, 0, stream>>>(xt, y1g, wte, be, out);
}